// Round 5
// baseline (349.054 us; speedup 1.0000x reference)
//
#include <hip/hip_runtime.h>
#include <hip/hip_cooperative_groups.h>

namespace cg = cooperative_groups;

#define D 768
#define CAP 64        // max layer-2 in-edges per target
#define MD1 32        // max in-degree for layer-1 match lists
#define MAXROWS 1040  // B + B*CAP worst case (B=16)
#define NI 24         // i-chunks in gemm (768 = 24*32)
#define IC 32         // i-chunk depth
#define NBLK 256      // cooperative grid: 1 block per CU
#define NEG 0.2f

struct KArgs {
    const float *x, *ef;
    const int *src, *dst, *goff;
    const float *W1, *We1, *b1, *W2, *We2, *b2;
    const float *al1, *ar1, *ae1, *al2, *ar2, *ae2;
    float* out;
    int E, B, nrows;
    float* v;
    int *l2e, *cnt, *Mp, *mcnt, *cnode, *cslot, *medge;
    float *aggS, *aggE, *ag2S, *ag2E, *h_t, *h_s, *part1, *part2;
};

__device__ __forceinline__ float block_reduce_sum(float v, float* scratch) {
    int lane = threadIdx.x & 63;
    int wid  = threadIdx.x >> 6;
    #pragma unroll
    for (int o = 32; o > 0; o >>= 1) v += __shfl_down(v, o, 64);
    if (lane == 0) scratch[wid] = v;
    __syncthreads();
    if (threadIdx.x == 0) {
        float r = 0.f;
        #pragma unroll
        for (int w = 0; w < 4; ++w) r += scratch[w];
        scratch[0] = r;
    }
    __syncthreads();
    float r = scratch[0];
    __syncthreads();
    return r;
}

// weight-stationary partial GEMM phase: blocks 0..3*NI-1
__device__ __forceinline__ void gemm_phase(const float* __restrict__ W,
                                           const float* __restrict__ We,
                                           const float* __restrict__ S,
                                           const float* __restrict__ Eg,
                                           int M, int Rmax, float* __restrict__ partial,
                                           int bid, int tid) {
    if (bid >= 3 * NI) return;
    int q = bid % 3, iy = bid / 3;
    int col = q * 256 + tid, i0 = iy * IC;
    float w[IC], we[IC];
    #pragma unroll
    for (int k = 0; k < IC; ++k) {
        w[k]  = W[(long)(i0 + k) * D + col];
        we[k] = We[(long)(i0 + k) * D + col];
    }
    float* pout = partial + (long)iy * Rmax * D + col;
    for (int r = 0; r < M; ++r) {
        const float* pS = S + (long)r * D + i0;
        const float* pE = Eg + (long)r * D + i0;
        float acc = 0.f;
        #pragma unroll
        for (int k = 0; k < IC; ++k) acc += pS[k] * w[k] + pE[k] * we[k];
        pout[(long)r * D] = acc;
    }
}

__global__ __launch_bounds__(256) void fused(KArgs a) {
    cg::grid_group grid = cg::this_grid();
    const int tid = threadIdx.x, bid = blockIdx.x;
    const int gsz = gridDim.x;

    __shared__ int   nodes[MAXROWS];
    __shared__ float red[8];
    __shared__ float matt[CAP];
    __shared__ int   msh[MD1], meh[MD1];
    __shared__ int   tg[32];

    // ---------- phase 0: zero counters span [cnt|Mp|mcnt] + projvec ----------
    {
        int n0 = a.B + 1 + a.nrows;
        for (int i = bid * 256 + tid; i < n0; i += gsz * 256) a.cnt[i] = 0;

        int gw = bid * 4 + (tid >> 6), lane = tid & 63, nW = gsz * 4;
        for (int task = gw; task < 4 * D; task += nW) {
            int g = task / D, i = task % D;
            const float* W; const float* p1; const float* p2 = nullptr; int o1 = 0, o2 = 0;
            switch (g) {
                case 0: W = a.W1;  p1 = a.al1; p2 = a.ar1; o1 = 0;     o2 = D;     break;
                case 1: W = a.We1; p1 = a.ae1;             o1 = 2 * D;             break;
                case 2: W = a.W2;  p1 = a.al2; p2 = a.ar2; o1 = 3 * D; o2 = 4 * D; break;
                default:W = a.We2; p1 = a.ae2;             o1 = 5 * D;             break;
            }
            float s1 = 0.f, s2 = 0.f;
            for (int j = lane; j < D; j += 64) {
                float w = W[(long)i * D + j];
                s1 += w * p1[j];
                if (p2) s2 += w * p2[j];
            }
            #pragma unroll
            for (int o = 32; o > 0; o >>= 1) {
                s1 += __shfl_down(s1, o, 64);
                s2 += __shfl_down(s2, o, 64);
            }
            if (lane == 0) { a.v[o1 + i] = s1; if (p2) a.v[o2 + i] = s2; }
        }
    }
    grid.sync();

    // ---------- phase 1: build layer-2 edge lists ----------
    {
        if (tid < a.B) tg[tid] = a.goff[tid];
        __syncthreads();
        for (int e = bid * 256 + tid; e < a.E; e += gsz * 256) {
            int d = a.dst[e];
            for (int b = 0; b < a.B; ++b) {
                if (d == tg[b]) {
                    int pos = atomicAdd(&a.cnt[b], 1);
                    if (pos < CAP) a.l2e[b * CAP + pos] = e;
                }
            }
        }
    }
    grid.sync();

    // ---------- phase 2: sort l2 lists + ballot-compact needed rows (block 0) ----------
    if (bid == 0) {
        int t = tid;
        if (t < a.B) {
            int n = a.cnt[t]; if (n > CAP) n = CAP; a.cnt[t] = n;
            int* L = a.l2e + t * CAP;
            for (int i = 1; i < n; ++i) {
                int k = L[i]; int j = i - 1;
                while (j >= 0 && L[j] > k) { L[j + 1] = L[j]; --j; }
                L[j + 1] = k;
            }
        }
        __syncthreads();
        if (t < 64) {
            int nslot = a.B + a.B * CAP;
            int base = 0;
            for (int s0 = 0; s0 < nslot; s0 += 64) {
                int s = s0 + t;
                bool valid = false; int node = -1;
                if (s < a.B) { valid = true; node = a.goff[s]; }
                else if (s < nslot) {
                    int rb = (s - a.B) >> 6, i = (s - a.B) & 63;   // CAP == 64
                    if (i < a.cnt[rb]) { valid = true; node = a.src[a.l2e[rb * CAP + i]]; }
                }
                unsigned long long m = __ballot(valid);
                if (valid) {
                    int ci = base + __popcll(m & ((1ULL << t) - 1));
                    a.cnode[ci] = node; a.cslot[ci] = s;
                }
                base += __popcll(m);
            }
            if (t == 0) *a.Mp = base;
        }
    }
    grid.sync();

    const int M = *a.Mp;

    // ---------- phase 3: match layer-1 in-edges of the compact node set ----------
    {
        for (int i = tid; i < M; i += 256) nodes[i] = a.cnode[i];
        __syncthreads();
        for (int e = bid * 256 + tid; e < a.E; e += gsz * 256) {
            int d = a.dst[e];
            for (int c = 0; c < M; ++c) {
                if (nodes[c] == d) {
                    int p = atomicAdd(&a.mcnt[c], 1);
                    if (p < MD1) a.medge[c * MD1 + p] = e;
                }
            }
        }
    }
    grid.sync();

    // ---------- phase 4: layer-1 attention + aggregation ----------
    {
        const float* val1 = a.v;
        const float* var1 = a.v + D;
        const float* vae1 = a.v + 2 * D;
        for (int c = bid; c < M; c += gsz) {
            int nm = a.mcnt[c]; if (nm > MD1) nm = MD1;
            int j = a.cnode[c];
            if (tid == 0) {  // sort by edge id -> deterministic
                int* L = a.medge + c * MD1;
                for (int a_ = 1; a_ < nm; ++a_) {
                    int k = L[a_]; int b = a_ - 1;
                    while (b >= 0 && L[b] > k) { L[b + 1] = L[b]; --b; }
                    L[b + 1] = k;
                }
                for (int k = 0; k < nm; ++k) { meh[k] = L[k]; msh[k] = a.src[L[k]]; }
            }
            __syncthreads();
            float p = 0.f;
            for (int cc = tid; cc < D; cc += 256) p += a.x[(long)j * D + cc] * var1[cc];
            float er_j = block_reduce_sum(p, red);
            for (int k = 0; k < nm; ++k) {
                float q = 0.f;
                for (int cc = tid; cc < D; cc += 256)
                    q += a.x[(long)msh[k] * D + cc] * val1[cc]
                       + a.ef[(long)meh[k] * D + cc] * vae1[cc];
                float tot = block_reduce_sum(q, red);
                if (tid == 0) {
                    tot += er_j;
                    matt[k] = tot >= 0.f ? tot : NEG * tot;
                }
            }
            __syncthreads();
            if (tid == 0) {
                float m = -1e30f;
                for (int k = 0; k < nm; ++k) m = fmaxf(m, matt[k]);
                float s = 0.f;
                for (int k = 0; k < nm; ++k) { matt[k] = expf(matt[k] - m); s += matt[k]; }
                float inv = s > 0.f ? 1.f / s : 0.f;
                for (int k = 0; k < nm; ++k) matt[k] *= inv;
            }
            __syncthreads();
            for (int cc = tid; cc < D; cc += 256) {
                float sx = 0.f, se = 0.f;
                for (int k = 0; k < nm; ++k) {
                    sx += matt[k] * a.x[(long)msh[k] * D + cc];
                    se += matt[k] * a.ef[(long)meh[k] * D + cc];
                }
                a.aggS[(long)c * D + cc] = sx;
                a.aggE[(long)c * D + cc] = se;
            }
            __syncthreads();  // protect shared lists before next row
        }
    }
    grid.sync();

    // ---------- phase 5: layer-1 partial GEMM ----------
    gemm_phase(a.W1, a.We1, a.aggS, a.aggE, M, a.nrows, a.part1, bid, tid);
    grid.sync();

    // ---------- phase 6: epilogue 1 (reduce partials + residual + bias + relu) ----------
    for (int t6 = bid; t6 < 3 * M; t6 += gsz) {
        int c = t6 / 3, q = t6 % 3;
        int col = q * 256 + tid;
        float acc = 0.f;
        for (int by = 0; by < NI; ++by)
            acc += a.part1[((long)by * a.nrows + c) * D + col];
        int j = a.cnode[c], slot = a.cslot[c];
        float h = acc + a.x[(long)j * D + col] + a.b1[col];
        h = h > 0.f ? h : 0.f;
        float* hdst = (slot < a.B) ? (a.h_t + (long)slot * D)
                                   : (a.h_s + (long)(slot - a.B) * D);
        hdst[col] = h;
    }
    grid.sync();

    // ---------- phase 7: layer-2 attention + aggregation ----------
    if (bid < a.B) {
        int b = bid;
        const float* val2 = a.v + 3 * D;
        const float* var2 = a.v + 4 * D;
        const float* vae2 = a.v + 5 * D;
        float p = 0.f;
        for (int cc = tid; cc < D; cc += 256) p += a.h_t[(long)b * D + cc] * var2[cc];
        float er2 = block_reduce_sum(p, red);
        int deg = a.cnt[b];
        for (int k = 0; k < deg; ++k) {
            int e = a.l2e[b * CAP + k];
            const float* hs = a.h_s + (long)(b * CAP + k) * D;
            float q = 0.f;
            for (int cc = tid; cc < D; cc += 256)
                q += hs[cc] * val2[cc] + a.ef[(long)e * D + cc] * vae2[cc];
            float tot = block_reduce_sum(q, red);
            if (tid == 0) {
                tot += er2;
                matt[k] = tot >= 0.f ? tot : NEG * tot;
            }
        }
        __syncthreads();
        if (tid == 0) {
            float m = -1e30f;
            for (int k = 0; k < deg; ++k) m = fmaxf(m, matt[k]);
            float s = 0.f;
            for (int k = 0; k < deg; ++k) { matt[k] = expf(matt[k] - m); s += matt[k]; }
            float inv = s > 0.f ? 1.f / s : 0.f;
            for (int k = 0; k < deg; ++k) matt[k] *= inv;
        }
        __syncthreads();
        for (int cc = tid; cc < D; cc += 256) {
            float sx = 0.f, se = 0.f;
            for (int k = 0; k < deg; ++k) {
                sx += matt[k] * a.h_s[(long)(b * CAP + k) * D + cc];
                se += matt[k] * a.ef[(long)a.l2e[b * CAP + k] * D + cc];
            }
            a.ag2S[(long)b * D + cc] = sx;
            a.ag2E[(long)b * D + cc] = se;
        }
    }
    grid.sync();

    // ---------- phase 8: layer-2 partial GEMM ----------
    gemm_phase(a.W2, a.We2, a.ag2S, a.ag2E, a.B, a.B, a.part2, bid, tid);
    grid.sync();

    // ---------- phase 9: epilogue 2 -> out ----------
    for (int t9 = bid; t9 < 3 * a.B; t9 += gsz) {
        int b = t9 / 3, q = t9 % 3;
        int col = q * 256 + tid;
        float acc = 0.f;
        for (int by = 0; by < NI; ++by)
            acc += a.part2[((long)by * a.B + b) * D + col];
        a.out[(long)b * D + col] = acc + a.h_t[(long)b * D + col] + a.b2[col];
    }
}

extern "C" void kernel_launch(void* const* d_in, const int* in_sizes, int n_in,
                              void* d_out, int out_size, void* d_ws, size_t ws_size,
                              hipStream_t stream) {
    KArgs a;
    a.x    = (const float*)d_in[0];
    a.ef   = (const float*)d_in[1];
    a.src  = (const int*)d_in[2];
    a.dst  = (const int*)d_in[3];
    a.goff = (const int*)d_in[4];
    a.W1   = (const float*)d_in[5];
    a.We1  = (const float*)d_in[6];
    a.al1  = (const float*)d_in[7];
    a.ar1  = (const float*)d_in[8];
    a.ae1  = (const float*)d_in[9];
    a.b1   = (const float*)d_in[10];
    a.W2   = (const float*)d_in[11];
    a.We2  = (const float*)d_in[12];
    a.al2  = (const float*)d_in[13];
    a.ar2  = (const float*)d_in[14];
    a.ae2  = (const float*)d_in[15];
    a.b2   = (const float*)d_in[16];
    a.out  = (float*)d_out;

    a.E = in_sizes[2];
    a.B = in_sizes[4];
    a.nrows = a.B + a.B * CAP;   // 1040

    float* ws = (float*)d_ws;
    a.v     = ws;                                   // 6*D
    a.l2e   = (int*)(a.v + 6 * D);                  // B*CAP
    a.cnt   = a.l2e + a.B * CAP;                    // B   } zeroed as one span
    a.Mp    = a.cnt + a.B;                          // 1   }
    a.mcnt  = a.Mp + 1;                             // nrows }
    a.cnode = a.mcnt + a.nrows;                     // nrows
    a.cslot = a.cnode + a.nrows;                    // nrows
    a.medge = a.cslot + a.nrows;                    // nrows*MD1
    a.aggS  = (float*)(a.medge + a.nrows * MD1);    // nrows*D
    a.aggE  = a.aggS + (long)a.nrows * D;           // nrows*D
    a.ag2S  = a.aggE + (long)a.nrows * D;           // B*D
    a.ag2E  = a.ag2S + (long)a.B * D;               // B*D
    a.h_t   = a.ag2E + (long)a.B * D;               // B*D
    a.h_s   = a.h_t + (long)a.B * D;                // B*CAP*D
    a.part1 = a.h_s + (long)a.B * CAP * D;          // NI*nrows*D
    a.part2 = a.part1 + (long)NI * a.nrows * D;     // NI*B*D

    void* params[] = { &a };
    hipLaunchCooperativeKernel((void*)fused, dim3(NBLK), dim3(256), params, 0, stream);
}

// Round 6
// 87.768 us; speedup vs baseline: 3.9770x; 3.9770x over previous
//
#include <hip/hip_runtime.h>

#define D 768
#define CAP 64        // max layer-2 in-edges per target
#define MD1 32        // max in-degree for layer-1 match lists
#define MAXROWS 1040  // B + B*CAP (B=16)
#define NI 24         // i-chunks (768 = 24*32)
#define IC 32         // i-chunk depth
#define NEG 0.2f

__device__ __forceinline__ float block_reduce_sum(float v, float* scratch) {
    int lane = threadIdx.x & 63;
    int wid  = threadIdx.x >> 6;
    #pragma unroll
    for (int o = 32; o > 0; o >>= 1) v += __shfl_down(v, o, 64);
    if (lane == 0) scratch[wid] = v;
    __syncthreads();
    if (threadIdx.x == 0) {
        float r = 0.f;
        #pragma unroll
        for (int w = 0; w < 4; ++w) r += scratch[w];
        scratch[0] = r;
    }
    __syncthreads();
    float r = scratch[0];
    __syncthreads();
    return r;
}

// A: zero counter span + projected attention vectors v[0..5][D]
__global__ __launch_bounds__(256) void init_proj(
        const float* W1, const float* We1, const float* W2, const float* We2,
        const float* al1, const float* ar1, const float* ae1,
        const float* al2, const float* ar2, const float* ae2,
        int* zspan, int nzero, float* v) {
    for (int i = blockIdx.x * 256 + threadIdx.x; i < nzero; i += gridDim.x * 256)
        zspan[i] = 0;
    int task = blockIdx.x * 4 + (threadIdx.x >> 6);
    int lane = threadIdx.x & 63;
    if (task >= 4 * D) return;
    int g = task / D, i = task % D;
    const float* W; const float* p1; const float* p2 = nullptr; int o1 = 0, o2 = 0;
    switch (g) {
        case 0: W = W1;  p1 = al1; p2 = ar1; o1 = 0;     o2 = D;     break;
        case 1: W = We1; p1 = ae1;           o1 = 2 * D;             break;
        case 2: W = W2;  p1 = al2; p2 = ar2; o1 = 3 * D; o2 = 4 * D; break;
        default:W = We2; p1 = ae2;           o1 = 5 * D;             break;
    }
    float s1 = 0.f, s2 = 0.f;
    for (int j = lane; j < D; j += 64) {
        float w = W[(long)i * D + j];
        s1 += w * p1[j];
        if (p2) s2 += w * p2[j];
    }
    #pragma unroll
    for (int o = 32; o > 0; o >>= 1) { s1 += __shfl_down(s1, o, 64); s2 += __shfl_down(s2, o, 64); }
    if (lane == 0) { v[o1 + i] = s1; if (p2) v[o2 + i] = s2; }
}

// B: find layer-2 edges (dst == a target), append per target
__global__ __launch_bounds__(256) void build_l2(
        const int* __restrict__ dst, const int* __restrict__ goff,
        int E, int B, int* l2e, int* cnt) {
    __shared__ int tg[32];
    if ((int)threadIdx.x < B) tg[threadIdx.x] = goff[threadIdx.x];
    __syncthreads();
    for (int e = blockIdx.x * 256 + threadIdx.x; e < E; e += gridDim.x * 256) {
        int d = dst[e];
        for (int b = 0; b < B; ++b) {
            if (d == tg[b]) {
                int pos = atomicAdd(&cnt[b], 1);
                if (pos < CAP) l2e[b * CAP + pos] = e;
            }
        }
    }
}

// C: match layer-1 in-edges of every valid slot's node; append keyed by slot
__global__ __launch_bounds__(256) void match_l1(
        const int* __restrict__ dst, const int* __restrict__ src,
        const int* __restrict__ goff, const int* __restrict__ l2e,
        const int* __restrict__ cnt, int E, int B, int* medge, int* mcnt) {
    __shared__ int tnode[MAXROWS], tslot[MAXROWS];
    __shared__ int tn;
    int tid = threadIdx.x;
    if (tid == 0) tn = 0;
    __syncthreads();
    int nslot = B + B * CAP;
    for (int s = tid; s < nslot; s += 256) {
        int node = -1; bool valid = false;
        if (s < B) { node = goff[s]; valid = true; }
        else {
            int rb = (s - B) >> 6, i = (s - B) & 63;
            int cb = cnt[rb]; if (cb > CAP) cb = CAP;
            if (i < cb) { node = src[l2e[rb * CAP + i]]; valid = true; }
        }
        if (valid) { int p = atomicAdd(&tn, 1); tnode[p] = node; tslot[p] = s; }
    }
    __syncthreads();
    int M = tn;
    for (int e = blockIdx.x * 256 + tid; e < E; e += gridDim.x * 256) {
        int d = dst[e];
        for (int c = 0; c < M; ++c) {
            if (tnode[c] == d) {
                int sl = tslot[c];
                int p = atomicAdd(&mcnt[sl], 1);
                if (p < MD1) medge[sl * MD1 + p] = e;
            }
        }
    }
}

// D: per valid slot: sort edges, logits, softmax -> matt1/msrc1; init h = x + b1
__global__ __launch_bounds__(256) void att1(
        const float* __restrict__ x, const float* __restrict__ ef,
        const int* __restrict__ src, const int* __restrict__ goff,
        const int* __restrict__ l2e, const int* __restrict__ cnt,
        const float* __restrict__ b1, const float* __restrict__ v,
        int* medge, const int* __restrict__ mcnt, int B,
        float* matt1, int* msrc1, float* h) {
    int s = blockIdx.x, tid = threadIdx.x;
    int j;
    if (s < B) j = goff[s];
    else {
        int rb = (s - B) >> 6, i = (s - B) & 63;
        int cb = cnt[rb]; if (cb > CAP) cb = CAP;
        if (i >= cb) return;
        j = src[l2e[rb * CAP + i]];
    }
    __shared__ float red[8];
    __shared__ float matt[MD1];
    __shared__ int meh[MD1], msh[MD1];
    int nm = mcnt[s]; if (nm > MD1) nm = MD1;
    if (tid == 0) {  // sort by edge id -> deterministic
        int* L = medge + s * MD1;
        for (int a_ = 1; a_ < nm; ++a_) {
            int k = L[a_]; int b = a_ - 1;
            while (b >= 0 && L[b] > k) { L[b + 1] = L[b]; --b; }
            L[b + 1] = k;
        }
        for (int k = 0; k < nm; ++k) {
            meh[k] = L[k]; msh[k] = src[L[k]];
            msrc1[s * MD1 + k] = msh[k];
        }
    }
    __syncthreads();
    const float* val1 = v;
    const float* var1 = v + D;
    const float* vae1 = v + 2 * D;
    float p = 0.f;
    for (int cc = tid; cc < D; cc += 256) p += x[(long)j * D + cc] * var1[cc];
    float er_j = block_reduce_sum(p, red);
    for (int k = 0; k < nm; ++k) {
        float q = 0.f;
        for (int cc = tid; cc < D; cc += 256)
            q += x[(long)msh[k] * D + cc] * val1[cc] + ef[(long)meh[k] * D + cc] * vae1[cc];
        float tot = block_reduce_sum(q, red);
        if (tid == 0) {
            tot += er_j;
            matt[k] = tot >= 0.f ? tot : NEG * tot;
        }
    }
    if (tid == 0) {
        float m = -1e30f;
        for (int k = 0; k < nm; ++k) m = fmaxf(m, matt[k]);
        float sum = 0.f;
        for (int k = 0; k < nm; ++k) { matt[k] = expf(matt[k] - m); sum += matt[k]; }
        float inv = sum > 0.f ? 1.f / sum : 0.f;
        for (int k = 0; k < nm; ++k) matt1[s * MD1 + k] = matt[k] * inv;
    }
    for (int col = tid; col < D; col += 256)
        h[(long)s * D + col] = x[(long)j * D + col] + b1[col];
}

// E: weight-stationary i-chunk GEMM, atomicAdd into h (4 rows staged per pass)
__global__ __launch_bounds__(256) void gemm1(
        const float* __restrict__ W1, const float* __restrict__ We1,
        const float* __restrict__ x, const float* __restrict__ ef,
        const int* __restrict__ cnt,
        const float* __restrict__ matt1, const int* __restrict__ msrc1,
        const int* __restrict__ medge1, const int* __restrict__ mcnt,
        float* h, int B) {
    __shared__ int vl[MAXROWS];
    __shared__ int vn_sh;
    __shared__ float scs[4][IC], ecs[4][IC];
    int tid = threadIdx.x;
    if (tid == 0) vn_sh = 0;
    __syncthreads();
    int nslot = B + B * CAP;
    for (int s = tid; s < nslot; s += 256) {
        bool valid;
        if (s < B) valid = true;
        else {
            int rb = (s - B) >> 6, i = (s - B) & 63;
            int cb = cnt[rb]; if (cb > CAP) cb = CAP;
            valid = i < cb;
        }
        if (valid) { int p = atomicAdd(&vn_sh, 1); vl[p] = s; }
    }
    __syncthreads();
    int vn = vn_sh;
    int q = blockIdx.x % 3, iy = blockIdx.x / 3;
    int col = q * 256 + tid, i0 = iy * IC;
    float w[IC], we[IC];
    #pragma unroll
    for (int k = 0; k < IC; ++k) {
        w[k]  = W1[(long)(i0 + k) * D + col];
        we[k] = We1[(long)(i0 + k) * D + col];
    }
    for (int g = 0; g < vn; g += 4) {
        int ri = g + (tid >> 6), lane = tid & 63;
        if (ri < vn) {
            int s = vl[ri];
            int nm = mcnt[s]; if (nm > MD1) nm = MD1;
            if (lane < 32) {
                float a = 0.f;
                for (int k = 0; k < nm; ++k)
                    a += matt1[s * MD1 + k] * x[(long)msrc1[s * MD1 + k] * D + i0 + lane];
                scs[tid >> 6][lane] = a;
            } else {
                float a = 0.f;
                for (int k = 0; k < nm; ++k)
                    a += matt1[s * MD1 + k] * ef[(long)medge1[s * MD1 + k] * D + i0 + lane - 32];
                ecs[tid >> 6][lane - 32] = a;
            }
        }
        __syncthreads();
        int gmax = vn - g; if (gmax > 4) gmax = 4;
        for (int rr = 0; rr < gmax; ++rr) {
            float acc = 0.f;
            #pragma unroll
            for (int k = 0; k < IC; ++k) acc += scs[rr][k] * w[k] + ecs[rr][k] * we[k];
            atomicAdd(&h[(long)vl[g + rr] * D + col], acc);
        }
        __syncthreads();
    }
}

// F: layer-2 logits/softmax (reads relu(h)); sorted order -> w2att/l2s/l2p; init out
__global__ __launch_bounds__(256) void att2(
        const float* __restrict__ ef, const int* __restrict__ l2e,
        const int* __restrict__ cnt, const float* __restrict__ b2,
        const float* __restrict__ v, const float* __restrict__ h,
        float* w2att, int* l2s, int* l2p, float* out, int B) {
    int b = blockIdx.x, tid = threadIdx.x;
    __shared__ int se[CAP], sp[CAP];
    __shared__ float matt[CAP];
    __shared__ float red[8];
    int deg = cnt[b]; if (deg > CAP) deg = CAP;
    if (tid == 0) {
        for (int i = 0; i < deg; ++i) { se[i] = l2e[b * CAP + i]; sp[i] = i; }
        for (int a_ = 1; a_ < deg; ++a_) {
            int ke = se[a_], kp = sp[a_]; int q = a_ - 1;
            while (q >= 0 && se[q] > ke) { se[q + 1] = se[q]; sp[q + 1] = sp[q]; --q; }
            se[q + 1] = ke; sp[q + 1] = kp;
        }
        for (int k = 0; k < deg; ++k) { l2s[b * CAP + k] = se[k]; l2p[b * CAP + k] = sp[k]; }
    }
    __syncthreads();
    const float* val2 = v + 3 * D;
    const float* var2 = v + 4 * D;
    const float* vae2 = v + 5 * D;
    float p = 0.f;
    for (int cc = tid; cc < D; cc += 256) p += fmaxf(h[(long)b * D + cc], 0.f) * var2[cc];
    float er2 = block_reduce_sum(p, red);
    for (int k = 0; k < deg; ++k) {
        const float* hs = h + (long)(B + b * CAP + sp[k]) * D;
        float q = 0.f;
        for (int cc = tid; cc < D; cc += 256)
            q += fmaxf(hs[cc], 0.f) * val2[cc] + ef[(long)se[k] * D + cc] * vae2[cc];
        float tot = block_reduce_sum(q, red);
        if (tid == 0) {
            tot += er2;
            matt[k] = tot >= 0.f ? tot : NEG * tot;
        }
    }
    if (tid == 0) {
        float m = -1e30f;
        for (int k = 0; k < deg; ++k) m = fmaxf(m, matt[k]);
        float sum = 0.f;
        for (int k = 0; k < deg; ++k) { matt[k] = expf(matt[k] - m); sum += matt[k]; }
        float inv = sum > 0.f ? 1.f / sum : 0.f;
        for (int k = 0; k < deg; ++k) w2att[b * CAP + k] = matt[k] * inv;
    }
    for (int col = tid; col < D; col += 256)
        out[(long)b * D + col] = fmaxf(h[(long)b * D + col], 0.f) + b2[col];
}

// G: layer-2 i-chunk GEMM, atomicAdd into out
__global__ __launch_bounds__(256) void gemm2(
        const float* __restrict__ W2, const float* __restrict__ We2,
        const float* __restrict__ ef, const float* __restrict__ h,
        const float* __restrict__ w2att, const int* __restrict__ l2s,
        const int* __restrict__ l2p, const int* __restrict__ cnt,
        float* out, int B) {
    __shared__ float scs[4][IC], ecs[4][IC];
    int tid = threadIdx.x;
    int q = blockIdx.x % 3, iy = blockIdx.x / 3;
    int col = q * 256 + tid, i0 = iy * IC;
    float w[IC], we[IC];
    #pragma unroll
    for (int k = 0; k < IC; ++k) {
        w[k]  = W2[(long)(i0 + k) * D + col];
        we[k] = We2[(long)(i0 + k) * D + col];
    }
    for (int g = 0; g < B; g += 4) {
        int r = g + (tid >> 6), lane = tid & 63;
        if (r < B) {
            int deg = cnt[r]; if (deg > CAP) deg = CAP;
            if (lane < 32) {
                float a = 0.f;
                for (int k = 0; k < deg; ++k)
                    a += w2att[r * CAP + k] *
                         fmaxf(h[(long)(B + r * CAP + l2p[r * CAP + k]) * D + i0 + lane], 0.f);
                scs[tid >> 6][lane] = a;
            } else {
                float a = 0.f;
                for (int k = 0; k < deg; ++k)
                    a += w2att[r * CAP + k] * ef[(long)l2s[r * CAP + k] * D + i0 + lane - 32];
                ecs[tid >> 6][lane - 32] = a;
            }
        }
        __syncthreads();
        int gmax = B - g; if (gmax > 4) gmax = 4;
        for (int rr = 0; rr < gmax; ++rr) {
            float acc = 0.f;
            #pragma unroll
            for (int k = 0; k < IC; ++k) acc += scs[rr][k] * w[k] + ecs[rr][k] * we[k];
            atomicAdd(&out[(long)(g + rr) * D + col], acc);
        }
        __syncthreads();
    }
}

extern "C" void kernel_launch(void* const* d_in, const int* in_sizes, int n_in,
                              void* d_out, int out_size, void* d_ws, size_t ws_size,
                              hipStream_t stream) {
    const float* x    = (const float*)d_in[0];
    const float* ef   = (const float*)d_in[1];
    const int*   src  = (const int*)d_in[2];
    const int*   dst  = (const int*)d_in[3];
    const int*   goff = (const int*)d_in[4];
    const float* W1   = (const float*)d_in[5];
    const float* We1  = (const float*)d_in[6];
    const float* al1  = (const float*)d_in[7];
    const float* ar1  = (const float*)d_in[8];
    const float* ae1  = (const float*)d_in[9];
    const float* b1   = (const float*)d_in[10];
    const float* W2   = (const float*)d_in[11];
    const float* We2  = (const float*)d_in[12];
    const float* al2  = (const float*)d_in[13];
    const float* ar2  = (const float*)d_in[14];
    const float* ae2  = (const float*)d_in[15];
    const float* b2   = (const float*)d_in[16];
    float* out = (float*)d_out;

    int E = in_sizes[2];
    int B = in_sizes[4];
    int nslot = B + B * CAP;   // 1040

    float* ws    = (float*)d_ws;
    float* v     = ws;                               // 6*D
    int*   l2e   = (int*)(v + 6 * D);                // B*CAP
    int*   cnt   = l2e + B * CAP;                    // B      } zero span
    int*   mcnt  = cnt + B;                          // nslot  }
    float* matt1 = (float*)(mcnt + nslot);           // nslot*MD1
    int*   msrc1 = (int*)(matt1 + nslot * MD1);      // nslot*MD1
    int*   medge = msrc1 + nslot * MD1;              // nslot*MD1
    float* w2att = (float*)(medge + nslot * MD1);    // B*CAP
    int*   l2s   = (int*)(w2att + B * CAP);          // B*CAP
    int*   l2p   = l2s + B * CAP;                    // B*CAP
    float* h     = (float*)(l2p + B * CAP);          // nslot*D

    int nzero = B + nslot;

    hipLaunchKernelGGL(init_proj, dim3(4 * D / 4), dim3(256), 0, stream,
                       W1, We1, W2, We2, al1, ar1, ae1, al2, ar2, ae2, cnt, nzero, v);
    hipLaunchKernelGGL(build_l2, dim3((E + 255) / 256), dim3(256), 0, stream,
                       dst, goff, E, B, l2e, cnt);
    hipLaunchKernelGGL(match_l1, dim3((E + 255) / 256), dim3(256), 0, stream,
                       dst, src, goff, l2e, cnt, E, B, medge, mcnt);
    hipLaunchKernelGGL(att1, dim3(nslot), dim3(256), 0, stream,
                       x, ef, src, goff, l2e, cnt, b1, v, medge, mcnt, B,
                       matt1, msrc1, h);
    hipLaunchKernelGGL(gemm1, dim3(3 * NI), dim3(256), 0, stream,
                       W1, We1, x, ef, cnt, matt1, msrc1, medge, mcnt, h, B);
    hipLaunchKernelGGL(att2, dim3(B), dim3(256), 0, stream,
                       ef, l2e, cnt, b2, v, h, w2att, l2s, l2p, out, B);
    hipLaunchKernelGGL(gemm2, dim3(3 * NI), dim3(256), 0, stream,
                       W2, We2, ef, h, w2att, l2s, l2p, cnt, out, B);
}